// Round 1
// baseline (309.080 us; speedup 1.0000x reference)
//
#include <hip/hip_runtime.h>

#define AHH 7
#define AWW 7
#define NS 49          // AH*AW
#define CC 256
#define HH 64
#define WW 64
#define ELEMS_PER_ROI (CC * NS)      // 12544
#define VEC4_PER_ROI (ELEMS_PER_ROI / 4)  // 3136

__global__ __launch_bounds__(256) void roialign_kernel(
    const float* __restrict__ features,
    const float* __restrict__ rois,
    float* __restrict__ out) {
  const int n   = blockIdx.x;
  const int tid = threadIdx.x;

  __shared__ int   s_off[NS];
  __shared__ float s_w00[NS], s_w01[NS], s_w10[NS], s_w11[NS];
  __shared__ int   s_base;

  if (tid < NS) {
    const float* roi = rois + n * 5;
    float bf = roi[0];
    float x1 = roi[1] * 0.0625f;
    float y1 = roi[2] * 0.0625f;
    float x2 = roi[3] * 0.0625f;
    float y2 = roi[4] * 0.0625f;
    float bin_h = fmaxf(y2 - y1, 0.0f) * (1.0f / 6.0f);
    float bin_w = fmaxf(x2 - x1, 0.0f) * (1.0f / 6.0f);
    int ph = tid / AWW;
    int pw = tid - ph * AWW;
    float h = y1 + (float)ph * bin_h;
    float w = x1 + (float)pw * bin_w;
    bool valid = (h >= 0.0f) && (h < (float)HH) && (w >= 0.0f) && (w < (float)WW);
    int h0 = min(max((int)floorf(h), 0), HH - 2);
    int w0 = min(max((int)floorf(w), 0), WW - 2);
    float lh = h - (float)h0;   // NOTE: may exceed 1 near top/right edge (matches reference)
    float lw = w - (float)w0;
    float w00 = (1.0f - lh) * (1.0f - lw);
    float w01 = (1.0f - lh) * lw;
    float w10 = lh * (1.0f - lw);
    float w11 = lh * lw;
    if (!valid) { w00 = 0.0f; w01 = 0.0f; w10 = 0.0f; w11 = 0.0f; }
    s_off[tid] = h0 * WW + w0;
    s_w00[tid] = w00; s_w01[tid] = w01; s_w10[tid] = w10; s_w11[tid] = w11;
    if (tid == 0) s_base = (int)bf * (CC * HH * WW);
  }
  __syncthreads();

  const float* fb = features + s_base;
  float4* ob = (float4*)(out + (size_t)n * ELEMS_PER_ROI);

  for (int i = tid; i < VEC4_PER_ROI; i += 256) {
    int f0 = i * 4;
    float r[4];
#pragma unroll
    for (int j = 0; j < 4; ++j) {
      int f = f0 + j;
      int c = f / NS;            // magic-multiply, compile-time constant divisor
      int s = f - c * NS;
      int off = s_off[s];
      const float* p = fb + (c << 12) + off;  // c * H*W = c*4096
      float v00 = p[0];
      float v01 = p[1];
      float v10 = p[WW];
      float v11 = p[WW + 1];
      r[j] = v00 * s_w00[s] + v01 * s_w01[s] + v10 * s_w10[s] + v11 * s_w11[s];
    }
    ob[i] = make_float4(r[0], r[1], r[2], r[3]);
  }
}

extern "C" void kernel_launch(void* const* d_in, const int* in_sizes, int n_in,
                              void* d_out, int out_size, void* d_ws, size_t ws_size,
                              hipStream_t stream) {
  const float* features = (const float*)d_in[0];
  const float* rois     = (const float*)d_in[1];
  float* out            = (float*)d_out;
  int N = in_sizes[1] / 5;   // 8000
  roialign_kernel<<<N, 256, 0, stream>>>(features, rois, out);
}